// Round 20
// baseline (762.256 us; speedup 1.0000x reference)
//
#include <hip/hip_runtime.h>
#include <hip/hip_bf16.h>
#include <stdint.h>

typedef __attribute__((ext_vector_type(8))) short short8_t;   // 8 x bf16 (4 VGPRs)
typedef __attribute__((ext_vector_type(4))) float f32x4;      // MFMA accum / nt vec

__device__ __forceinline__ unsigned short f2bf(float f) {
  union { float f; unsigned int u; } a;
  a.f = f;
  unsigned int u = a.u;
  u += 0x7fffu + ((u >> 16) & 1u);   // round-to-nearest-even
  return (unsigned short)(u >> 16);
}

__device__ __forceinline__ void gload_lds16(const void* g, void* l) {
  __builtin_amdgcn_global_load_lds(
      (const __attribute__((address_space(1))) void*)g,
      (__attribute__((address_space(3))) void*)l, 16, 0, 0);
}

// ---------------- LayerNorm: fp32 -> bf16 normed rows ----------------
constexpr int D_IN = 4096;

__global__ __launch_bounds__(256) void ln_bf16_kernel(
    const float* __restrict__ x, const float* __restrict__ lnw,
    const float* __restrict__ lnb, unsigned short* __restrict__ out) {
  const int row = blockIdx.x;
  const int tid = threadIdx.x;
  const float* xr = x + (size_t)row * D_IN;

  f32x4 v[4];
  float sum = 0.f, sq = 0.f;
#pragma unroll
  for (int i = 0; i < 4; ++i) {
    v[i] = __builtin_nontemporal_load(
        reinterpret_cast<const f32x4*>(xr + i * 1024 + tid * 4));
    sum += v[i][0] + v[i][1] + v[i][2] + v[i][3];
    sq += v[i][0]*v[i][0] + v[i][1]*v[i][1] + v[i][2]*v[i][2] + v[i][3]*v[i][3];
  }
#pragma unroll
  for (int off = 32; off > 0; off >>= 1) {
    sum += __shfl_down(sum, off, 64);
    sq  += __shfl_down(sq, off, 64);
  }
  __shared__ float s_sum[4], s_sq[4];
  if ((tid & 63) == 0) { s_sum[tid >> 6] = sum; s_sq[tid >> 6] = sq; }
  __syncthreads();
  const float fs = s_sum[0] + s_sum[1] + s_sum[2] + s_sum[3];
  const float fq = s_sq[0] + s_sq[1] + s_sq[2] + s_sq[3];
  const float mean = fs * (1.f / D_IN);
  const float var = fq * (1.f / D_IN) - mean * mean;
  const float rstd = rsqrtf(var + 1e-5f);

  unsigned short* orow = out + (size_t)row * D_IN;
#pragma unroll
  for (int i = 0; i < 4; ++i) {
    const int col = i * 1024 + tid * 4;
    const f32x4 w = *reinterpret_cast<const f32x4*>(lnw + col);
    const f32x4 b = *reinterpret_cast<const f32x4*>(lnb + col);
    ushort4 o;
    o.x = f2bf((v[i][0] - mean) * rstd * w[0] + b[0]);
    o.y = f2bf((v[i][1] - mean) * rstd * w[1] + b[1]);
    o.z = f2bf((v[i][2] - mean) * rstd * w[2] + b[2]);
    o.w = f2bf((v[i][3] - mean) * rstd * w[3] + b[3]);
    *reinterpret_cast<ushort4*>(orow + col) = o;
  }
}

// ---------------- Weight cast fp32 -> bf16 ----------------
__global__ __launch_bounds__(256) void f32_to_bf16_kernel(
    const float* __restrict__ in, unsigned short* __restrict__ out) {
  const size_t i = ((size_t)blockIdx.x * 256 + threadIdx.x) * 8;
  const f32x4 a = __builtin_nontemporal_load(reinterpret_cast<const f32x4*>(in + i));
  const f32x4 b = __builtin_nontemporal_load(reinterpret_cast<const f32x4*>(in + i + 4));
  ushort4 lo, hi;
  lo.x = f2bf(a[0]); lo.y = f2bf(a[1]); lo.z = f2bf(a[2]); lo.w = f2bf(a[3]);
  hi.x = f2bf(b[0]); hi.y = f2bf(b[1]); hi.z = f2bf(b[2]); hi.w = f2bf(b[3]);
  *reinterpret_cast<ushort4*>(out + i) = lo;
  *reinterpret_cast<ushort4*>(out + i + 4) = hi;
}

// ---------------- 256x128 bf16 GEMM: 256-thr blocks, 2 blocks/CU ------
// C = A(MxK) * B(NxK)^T + bias.  256 thr = 4 waves (2M x 2N), per-wave
// 128x64 out (r12's exact per-wave register & LDS-traffic economy:
// 0.0229 B/FLOP).  BK=64.  LDS 64 KiB: A single-buf @ 0 (32K), B dbuf
// @ 32K/48K (16K each)  ->  TWO blocks/CU with INDEPENDENT barriers.
// MECHANISM (the untested matrix cell): r12's serial sum (LDS floor 361us
// + MFMA floor 379us) comes from one block-wide barrier convoy; r16 proved
// 2 independent blocks/CU overlap the two pipes.  Here each SIMD hosts one
// wave from EACH block: block A in read/barrier phase while block B MFMAs.
// Registers: 2 waves/SIMD -> 256-reg cap; acc 128 AGPR + 48 frag + ~20
// addr = no spill (r12-proven profile; r13/r18 spilled only at the
// 128-cap of 4 waves/SIMD).
// Schedule (r18's race-audited X/Y):
//  X(k): READ12 kk0 (8A+4B) -> MFMA32 -> READ12 kk1; lgkm(0)+bar
//        => A(k),B(k) fully read by all waves -> restage safe.
//  Y(k): stage A(k+1) (8x4KB) + B(k+2)->slot k&1 (4x4KB); MFMA32 (kk1,
//        operands drained); vmcnt(4)+bar => A(k+1),B(k+1) landed,
//        B(k+2)'s 4 loads keep a full region of latency cover.
// Swizzle byte ^= ((row&7)<<4): 0 conflicts (r6-verified read shape).

#define RD(P, IMM) (*reinterpret_cast<const short8_t*>((P) + (IMM)))

#define READ12(S, KK)                                               \
  _Pragma("unroll") for (int m_ = 0; m_ < 8; ++m_)                  \
    af[m_] = RD((KK) ? aB1 : aB0, m_*2048);                         \
  _Pragma("unroll") for (int n_ = 0; n_ < 4; ++n_)                  \
    bfr[n_] = RD((KK) ? bB1 : bB0, (S)*16384 + n_*2048);

#define MFMA32                                                      \
  _Pragma("unroll") for (int m_ = 0; m_ < 8; ++m_) {                \
    _Pragma("unroll") for (int n_ = 0; n_ < 4; ++n_)                \
      acc[m_][n_] = __builtin_amdgcn_mfma_f32_16x16x32_bf16(        \
          af[m_], bfr[n_], acc[m_][n_], 0, 0, 0);                   \
  }

// stage unit = 32 rows = 4KB (256 thr x 16B); per-wave dest base +wid*1024
#define STAGE_A8(KT)                                                \
  _Pragma("unroll") for (int u_ = 0; u_ < 8; ++u_)                  \
    gload_lds16(aSrc + (size_t)(u_*32) * K + (size_t)(KT)*64, ldsAw + u_*4096);
#define STAGE_B4(S, KT)                                             \
  _Pragma("unroll") for (int u_ = 0; u_ < 4; ++u_)                  \
    gload_lds16(bSrc + (size_t)(u_*32) * K + (size_t)(KT)*64, ldsBw + (S)*16384 + u_*4096);

// X: reads + kk0 MFMAs + kk1 reads; read-complete (stage-WAR) gate
#define XREG(S)                                                     \
  READ12(S, 0)                                                      \
  __builtin_amdgcn_s_setprio(1);                                    \
  MFMA32                                                            \
  __builtin_amdgcn_s_setprio(0);                                    \
  READ12(S, 1)                                                      \
  asm volatile("s_waitcnt lgkmcnt(0)" ::: "memory");                \
  __builtin_amdgcn_s_barrier();                                     \
  asm volatile("" ::: "memory");

// Y: restage A(k+1) + B(k+2); kk1 MFMAs (wait-free); counted-vmcnt gate
#define YREG(S, KTA, KTB)                                           \
  STAGE_A8(KTA)                                                     \
  STAGE_B4(S, KTB)                                                  \
  __builtin_amdgcn_s_setprio(1);                                    \
  MFMA32                                                            \
  __builtin_amdgcn_s_setprio(0);                                    \
  asm volatile("s_waitcnt vmcnt(4)" ::: "memory");                  \
  __builtin_amdgcn_s_barrier();                                     \
  asm volatile("" ::: "memory");

__global__ __launch_bounds__(256, 2) void gemm_2blk(
    const unsigned short* __restrict__ A,   // M x K bf16
    const unsigned short* __restrict__ B,   // N x K bf16
    const float* __restrict__ bias,         // N fp32
    float* __restrict__ C,                  // M x N fp32
    int M, int N, int K, int NYB, int BXP) {
  extern __shared__ char smem[];
  const int tid = threadIdx.x;
  const int lane = tid & 63;
  const int wid = tid >> 6;                 // 0..3
  const int wr = wid >> 1, wc = wid & 1;    // 2M x 2N waves
  const int fr = lane & 15;
  const int q16 = (lane >> 4) * 16;

  // Super-tiled XCD mapping: window per XCD = 8(by) x BXP(bx)
  const int id = blockIdx.x;
  const int xcd = id & 7;
  const int s = id >> 3;
  const int gsz = 8 * BXP;
  const int g = s / gsz;
  const int j = s - g * gsz;
  const int by = g * 8 + (j & 7);
  const int bx = xcd * BXP + (j >> 3);
  const int m0 = by * 256, n0 = bx * 128;

  // inverse-swizzled global source for linear global_load_lds dest
  const int s_log = (tid * 16) ^ (((tid >> 3) & 7) << 4);
  const int rsw = s_log >> 7;               // 0..31 (32-row stage unit)
  const int csw = (s_log & 127) >> 1;
  const unsigned short* aSrc = A + (size_t)(m0 + rsw) * K + csw;
  const unsigned short* bSrc = B + (size_t)(n0 + rsw) * K + csw;

  char* const ldsAw = smem + wid * 1024;            // wave-uniform stage bases
  char* const ldsBw = smem + 32768 + wid * 1024;

  // fragment lane-base pointers (swizzle byte ^= (row&7)<<4)
  const int s7 = (fr & 7) << 4;
  const char* const aB0 = smem + (wr * 128 + fr) * 128 + (q16 ^ s7);
  const char* const aB1 = smem + (wr * 128 + fr) * 128 + ((64 + q16) ^ s7);
  const char* const bB0 = smem + 32768 + (wc * 64 + fr) * 128 + (q16 ^ s7);
  const char* const bB1 = smem + 32768 + (wc * 64 + fr) * 128 + ((64 + q16) ^ s7);

  f32x4 acc[8][4] = {};            // 128 -> AGPR
  short8_t af[8], bfr[4];          // 48 VGPR, kk-rotated

  // ---- prologue: A(0); B(0)->slot0; B(1)->slot1 ----
  STAGE_A8(0)
  STAGE_B4(0, 0)
  STAGE_B4(1, 1)
  asm volatile("s_waitcnt vmcnt(4)" ::: "memory");   // A(0),B(0) landed
  __builtin_amdgcn_s_barrier();
  asm volatile("" ::: "memory");

  const int NK = K >> 6;   // BK=64 ktiles (even, >= 4)
  for (int t = 0; t < (NK - 2) >> 1; ++t) {
    const int k0 = 2*t, k1 = 2*t + 1;
    XREG(0) YREG(0, k0 + 1, k0 + 2)    // ktile k0: stage A(k0+1), B(k0+2)
    XREG(1) YREG(1, k1 + 1, k1 + 2)    // ktile k1: stage A(k1+1), B(k1+2)
  }
  // ---- tail: ktiles NK-2 (slot0), NK-1 (slot1) ----
  {
    XREG(0)
    STAGE_A8(NK - 1)                   // only A remains to stage
    __builtin_amdgcn_s_setprio(1);
    MFMA32
    __builtin_amdgcn_s_setprio(0);
    asm volatile("s_waitcnt vmcnt(0)" ::: "memory");
    __builtin_amdgcn_s_barrier();      // A(NK-1), B(NK-1) landed & published
    asm volatile("" ::: "memory");
    READ12(1, 0)
    __builtin_amdgcn_s_setprio(1);
    MFMA32
    __builtin_amdgcn_s_setprio(0);
    READ12(1, 1)
    __builtin_amdgcn_s_setprio(1);
    MFMA32                             // compiler counted-lgkm protects
    __builtin_amdgcn_s_setprio(0);
  }

  // ---- epilogue: direct nt stores (r16-proven clean write pattern) ----
  const int fq = lane >> 4;
  float bv[4];
#pragma unroll
  for (int n = 0; n < 4; ++n) bv[n] = bias[n0 + wc * 64 + n * 16 + fr];
#pragma unroll
  for (int m = 0; m < 8; ++m) {
#pragma unroll
    for (int jj = 0; jj < 4; ++jj) {
      const int row = m0 + wr * 128 + m * 16 + fq * 4 + jj;
      float* Crow = C + (size_t)row * N + n0 + wc * 64 + fr;
#pragma unroll
      for (int n = 0; n < 4; ++n)
        __builtin_nontemporal_store(acc[m][n][jj] + bv[n], Crow + n * 16);
    }
  }
}

extern "C" void kernel_launch(void* const* d_in, const int* in_sizes, int n_in,
                              void* d_out, int out_size, void* d_ws, size_t ws_size,
                              hipStream_t stream) {
  const float* x    = (const float*)d_in[0];
  const float* w    = (const float*)d_in[1];
  const float* bias = (const float*)d_in[2];
  const float* lnw  = (const float*)d_in[3];
  const float* lnb  = (const float*)d_in[4];
  float* out = (float*)d_out;

  const int DIN  = 4096;
  const int M    = in_sizes[0] / DIN;      // 8192
  const int DOUT = in_sizes[2];            // 12288

  unsigned short* normA = (unsigned short*)d_ws;                 // M x DIN bf16
  unsigned short* wB    = normA + (size_t)M * DIN;               // DOUT x DIN bf16

  ln_bf16_kernel<<<M, 256, 0, stream>>>(x, lnw, lnb, normA);
  f32_to_bf16_kernel<<<((size_t)DOUT * DIN) / (256 * 8), 256, 0, stream>>>(w, wB);

  const int nwg = (M / 256) * (DOUT / 128);   // 32 x 96 = 3072
  (void)hipFuncSetAttribute((const void*)gemm_2blk,
                            hipFuncAttributeMaxDynamicSharedMemorySize, 65536);
  gemm_2blk<<<nwg, 256, 65536, stream>>>(normA, wB, bias, out,
                                         M, DOUT, DIN, M / 256, (DOUT / 128) / 8);
}